// Round 8
// baseline (373.977 us; speedup 1.0000x reference)
//
#include <hip/hip_runtime.h>
#include <hip/hip_bf16.h>
#include <math.h>

#define B_   4
#define T_   4096
#define DIN_ 1024
#define H_   16
#define D_   64
#define M_   (B_*T_)      // 16384
#define N_   (H_*D_*2)    // 2048
#define K_   DIN_         // 1024
#define C_   64           // scan chunks per (b,h) chain
#define CL_  (T_/C_)      // 64 steps per chunk

typedef unsigned short u16;
typedef __attribute__((ext_vector_type(8))) short short8_t;
typedef __attribute__((ext_vector_type(4))) float float4_t;

__device__ __forceinline__ u16 f2bf(float f) {
  unsigned int x = __float_as_uint(f);
  x += 0x7fffu + ((x >> 16) & 1u);   // round-to-nearest-even (finite inputs)
  return (u16)(x >> 16);
}
__device__ __forceinline__ float bf2f(unsigned int u) {
  return __uint_as_float((u & 0xffffu) << 16);
}

// ---------------- prep: cast inputs + cast-transpose weights, one launch ----------------
__global__ __launch_bounds__(256)
void prep(const float* __restrict__ inputs, const float* __restrict__ kvk,
          u16* __restrict__ aB, u16* __restrict__ wBt) {
  __shared__ float tile[32][33];
  int bid = blockIdx.x;
  int tid = threadIdx.x;
  if (bid < 8192) {
    int i = bid * 256 + tid;          // over M*K/8
    const float4* src = (const float4*)inputs;
    float4 a = src[2*i], b = src[2*i+1];
    uint4 o;
    o.x = (unsigned)f2bf(a.x) | ((unsigned)f2bf(a.y) << 16);
    o.y = (unsigned)f2bf(a.z) | ((unsigned)f2bf(a.w) << 16);
    o.z = (unsigned)f2bf(b.x) | ((unsigned)f2bf(b.y) << 16);
    o.w = (unsigned)f2bf(b.z) | ((unsigned)f2bf(b.w) << 16);
    ((uint4*)aB)[i] = o;
  } else {
    int b2 = bid - 8192;              // 2048 blocks
    int kb = (b2 & 31) * 32;          // K/32 = 32
    int nb = (b2 >> 5) * 32;          // N/32 = 64
    int r  = tid >> 3;                // 0..31
    int c4 = (tid & 7) * 4;           // 0..28
    float4 v = *(const float4*)&kvk[(size_t)(kb + r) * N_ + nb + c4];
    tile[r][c4+0] = v.x; tile[r][c4+1] = v.y; tile[r][c4+2] = v.z; tile[r][c4+3] = v.w;
    __syncthreads();
    unsigned lo = (unsigned)f2bf(tile[c4+0][r]) | ((unsigned)f2bf(tile[c4+1][r]) << 16);
    unsigned hi = (unsigned)f2bf(tile[c4+2][r]) | ((unsigned)f2bf(tile[c4+3][r]) << 16);
    uint2 o; o.x = lo; o.y = hi;
    *(uint2*)&wBt[(size_t)(nb + r) * K_ + kb + c4] = o;
  }
}

// ---------------- GEMM + relu + s-dot + v-store + chunk-aggregate scan ----------------
// 1D grid 2048, XCD-swizzled: g -> xcd=g&7, slot=g>>3, head=slot&15, mtile=(slot>>4)*8+xcd.
// K-loop: NO LDS, NO barriers — A/B fragments loaded global->VGPR (L1/L2-served;
// B panel shared by 16 same-XCD blocks, A rows shared by 2 waves via L1).
// Pure dataflow: compiler pipelines loads across iters; TLP covers L2 latency.
__global__ __launch_bounds__(256)
void gemm_kv(const u16* __restrict__ A, const u16* __restrict__ Bt,
             const float* __restrict__ q,
             float* __restrict__ sbuf, u16* __restrict__ vbuf,
             float* __restrict__ aggM, float* __restrict__ aggU,
             float* __restrict__ aggW) {
  __shared__ u16  vtile[128][72];    // 18432 B (epilogue)
  __shared__ float sred[128][17];    //  8704 B (epilogue)
  __shared__ float qs[D_];
  __shared__ float sS[128];

  const int tid  = threadIdx.x;
  const int wave = tid >> 6;
  const int lane = tid & 63;
  const int quad = lane >> 4;
  const int l16  = lane & 15;

  const int g    = blockIdx.x;
  const int xcd  = g & 7;
  const int slot = g >> 3;
  const int h    = slot & 15;
  const int mt   = (slot >> 4) * 8 + xcd;   // 0..127
  const int bm = mt * 128;
  const int bn = h * 128;
  const int wm = (wave >> 1) * 64;
  const int wn = (wave & 1) * 64;

  if (tid < D_) qs[tid] = q[h * D_ + tid];

  // per-lane fragment base pointers (quad folded in); k advances by +64 elems/iter,
  // the two k-halves are +0 / +32 elem immediates (64 B) off the base.
  const u16* aP[4];
  const u16* bP[4];
#pragma unroll
  for (int i = 0; i < 4; ++i)
    aP[i] = A + (size_t)(bm + wm + i*16 + l16) * K_ + quad*8;
#pragma unroll
  for (int j = 0; j < 4; ++j)
    bP[j] = Bt + (size_t)(bn + wn + j*16 + l16) * K_ + quad*8;

  float4_t acc[4][4] = {};

  for (int it = 0; it < 16; ++it) {
    short8_t af[4][2], bfr[4][2];
#pragma unroll
    for (int i = 0; i < 4; ++i) {
      af[i][0] = *(const short8_t*)(aP[i]);
      af[i][1] = *(const short8_t*)(aP[i] + 32);
    }
#pragma unroll
    for (int j = 0; j < 4; ++j) {
      bfr[j][0] = *(const short8_t*)(bP[j]);
      bfr[j][1] = *(const short8_t*)(bP[j] + 32);
    }
#pragma unroll
    for (int t = 0; t < 2; ++t)
#pragma unroll
      for (int i = 0; i < 4; ++i)
#pragma unroll
        for (int j = 0; j < 4; ++j)
          acc[i][j] = __builtin_amdgcn_mfma_f32_16x16x32_bf16(af[i][t], bfr[j][t], acc[i][j], 0, 0, 0);
#pragma unroll
    for (int i = 0; i < 4; ++i) aP[i] += 64;
#pragma unroll
    for (int j = 0; j < 4; ++j) bP[j] += 64;
  }

  // ---- epilogue (unchanged from R7) ----
  // C/D layout: col(n)=l16, row(m)=quad*4+reg. n parity = l16 parity:
  // odd l16 -> v columns (stage bf16 to vtile), even l16 -> k columns (dot with q).
  if (l16 & 1) {
#pragma unroll
    for (int j = 0; j < 4; ++j) {
      int d = ((wn + j*16 + l16) & 127) >> 1;
#pragma unroll
      for (int i = 0; i < 4; ++i)
#pragma unroll
        for (int r = 0; r < 4; ++r) {
          int t = wm + i*16 + quad*4 + r;
          vtile[t][d] = f2bf(fmaxf(acc[i][j][r], 0.f));
        }
    }
  } else {
    int slot2 = (wn >> 3) + (l16 >> 1);   // 0..15
#pragma unroll
    for (int i = 0; i < 4; ++i)
#pragma unroll
      for (int r = 0; r < 4; ++r) {
        int t = wm + i*16 + quad*4 + r;
        float p = 0.f;
#pragma unroll
        for (int j = 0; j < 4; ++j) {
          int d = ((wn + j*16 + l16) & 127) >> 1;
          p += qs[d] * fmaxf(acc[i][j][r], 0.f);
        }
        sred[t][slot2] = p;
      }
  }
  __syncthreads();

  const int b   = mt >> 5;            // 32 m-tiles per batch
  const int tt0 = (mt & 31) * 128;    // t offset within batch
  const int bh  = b * H_ + h;

  // s reduction -> sS + sbuf
  if (tid < 128) {
    float ssum = 0.f;
#pragma unroll
    for (int k = 0; k < 16; ++k) ssum += sred[tid][k];
    sS[tid] = ssum;
    sbuf[(size_t)bh * T_ + tt0 + tid] = ssum;
  }
  __syncthreads();

  if (wave < 2) {
    // fused pass1: scan chunk `wave` (local t = wave*64 .. +63)
    int d = lane;
    float m = -INFINITY, u = 0.f, w = 0.f;
#pragma unroll 4
    for (int i = 0; i < CL_; ++i) {
      int t = wave * CL_ + i;
      float si = sS[t];
      float v  = bf2f(vtile[t][d]);
      float mn    = fmaxf(m, si);
      float alpha = __expf(m - mn);
      float p     = __expf(si - mn);
      u = u * alpha + p;
      w = w * alpha + p * v;
      m = mn;
    }
    int blk = bh * C_ + (mt & 31) * 2 + wave;
    aggW[(size_t)blk * D_ + d] = w;
    if (d == 0) { aggM[blk] = m; aggU[blk] = u; }
  } else {
    // coalesced v store: v[b][h][tt0:tt0+128][:] (contiguous 16 KB)
    int idx = tid - 128;               // 0..127
    int d0  = (idx & 7) * 8;
    int tr  = idx >> 3;                // 0..15
    u16* vg = vbuf + ((size_t)bh * T_ + tt0) * D_;
#pragma unroll
    for (int itv = 0; itv < 8; ++itv) {
      int t = tr + 16*itv;
      uint4 val = *(const uint4*)&vtile[t][d0];
      *(uint4*)&vg[(size_t)t * D_ + d0] = val;
    }
  }
}

// ---------------- pass 3: prefix + seeded scan + h-reduction ----------------
__global__ __launch_bounds__(1024)
void scan_pass3(const u16* __restrict__ vbuf, const float* __restrict__ sbuf,
                const float* __restrict__ aggM, const float* __restrict__ aggU,
                const float* __restrict__ aggW, float* __restrict__ out) {
  __shared__ float sS[H_][CL_];         // 4 KB
  __shared__ float wbuf[H_][8][D_ + 1]; // 33.3 KB
  int bc = blockIdx.x;
  int b  = bc >> 6;
  int c  = bc & (C_ - 1);
  int tid  = threadIdx.x;
  int h    = tid >> 6;
  int lane = tid & 63;
  int bh   = b * H_ + h;
  int t0   = c * CL_;

  sS[h][lane] = sbuf[(size_t)bh * T_ + t0 + lane];

  // exclusive prefix over chunks [0,c) of this chain
  float m = -INFINITY, u = 0.f, w = 0.f;
  for (int j = 0; j < c; ++j) {
    int idx = bh * C_ + j;
    float Mc = aggM[idx];
    float Uc = aggU[idx];
    float Wc = aggW[(size_t)idx * D_ + lane];
    float mn = fmaxf(m, Mc);
    float ea = __expf(m - mn);
    float eb = __expf(Mc - mn);
    u = u * ea + Uc * eb;
    w = w * ea + Wc * eb;
    m = mn;
  }
  __syncthreads();

  const u16* vp = vbuf + ((size_t)bh * T_ + t0) * D_ + lane;
  for (int gg = 0; gg < 8; ++gg) {
#pragma unroll
    for (int ii = 0; ii < 8; ++ii) {
      int i = gg * 8 + ii;
      float si = sS[h][i];
      float v  = bf2f(vp[i * D_]);
      float mn    = fmaxf(m, si);
      float alpha = __expf(m - mn);
      float p     = __expf(si - mn);
      u = u * alpha + p;
      w = w * alpha + p * v;
      m = mn;
      wbuf[h][ii][lane] = __fdividef(w, u);
    }
    __syncthreads();
    if (tid < 512) {
      int ii = tid >> 6, dd = tid & 63;
      float acc = 0.f;
#pragma unroll
      for (int hh = 0; hh < H_; ++hh) acc += wbuf[hh][ii][dd];
      out[((size_t)b * T_ + t0 + gg*8 + ii) * D_ + dd] = acc;
    }
    __syncthreads();
  }
}

extern "C" void kernel_launch(void* const* d_in, const int* in_sizes, int n_in,
                              void* d_out, int out_size, void* d_ws, size_t ws_size,
                              hipStream_t stream) {
  const float* inputs = (const float*)d_in[0];   // (B,T,DIN)
  const float* kvk    = (const float*)d_in[1];   // (DIN,H,D,2)
  const float* qk     = (const float*)d_in[2];   // (H,D)
  float* out = (float*)d_out;
  char* ws = (char*)d_ws;

  u16*   aB   = (u16*)ws;                       // 33,554,432 B  inputs bf16 [M][K]
  u16*   wBt  = (u16*)(ws + 33554432);          //  4,194,304 B  weights bf16 [N][K]
  u16*   vb   = (u16*)(ws + 37748736);          // 33,554,432 B  v bf16 [b,h,t,d]
  float* sb   = (float*)(ws + 71303168);        //  1,048,576 B  s [b,h,t]
  float* aggM = (float*)(ws + 72351744);        //     16,384 B
  float* aggU = (float*)(ws + 72368128);        //     16,384 B
  float* aggW = (float*)(ws + 72384512);        //  1,048,576 B  (ends ~73.4 MB)

  prep<<<10240, 256, 0, stream>>>(inputs, kvk, aB, wBt);
  gemm_kv<<<2048, 256, 0, stream>>>(aB, wBt, qk, sb, vb, aggM, aggU, aggW);
  scan_pass3<<<B_*C_, 1024, 0, stream>>>(vb, sb, aggM, aggU, aggW, out);
}

// Round 9
// 253.196 us; speedup vs baseline: 1.4770x; 1.4770x over previous
//
#include <hip/hip_runtime.h>
#include <hip/hip_bf16.h>
#include <math.h>

#define B_   4
#define T_   4096
#define DIN_ 1024
#define H_   16
#define D_   64
#define M_   (B_*T_)      // 16384
#define N_   (H_*D_*2)    // 2048
#define K_   DIN_         // 1024
#define C_   64           // scan chunks per (b,h) chain
#define CL_  (T_/C_)      // 64 steps per chunk

typedef unsigned short u16;
typedef __attribute__((ext_vector_type(8))) short short8_t;
typedef __attribute__((ext_vector_type(4))) float float4_t;

__device__ __forceinline__ u16 f2bf(float f) {
  unsigned int x = __float_as_uint(f);
  x += 0x7fffu + ((x >> 16) & 1u);   // round-to-nearest-even (finite inputs)
  return (u16)(x >> 16);
}
__device__ __forceinline__ float bf2f(unsigned int u) {
  return __uint_as_float((u & 0xffffu) << 16);
}
// pack two f32 -> bf16x2 (RNE), single v_cvt_pk_bf16_f32 on gfx950
__device__ __forceinline__ unsigned pk_bf16(float x, float y) {
  float2 f; f.x = x; f.y = y;
  union { __hip_bfloat162 h2; unsigned u; } c;
  c.h2 = __float22bfloat162_rn(f);
  return c.u;
}

// async global->LDS, 16 B per lane. LDS dest = wave-uniform base + lane*16.
__device__ __forceinline__ void g2l16(const u16* g, u16* l) {
  __builtin_amdgcn_global_load_lds(
      (const __attribute__((address_space(1))) void*)g,
      (__attribute__((address_space(3))) void*)l, 16, 0, 0);
}

// ---------------- prep: cast-transpose weights only ----------------
// weights [K][N] f32 -> [N][K] bf16 via 32x32 LDS tile; 2048 blocks
__global__ __launch_bounds__(256)
void prep(const float* __restrict__ kvk, u16* __restrict__ wBt) {
  __shared__ float tile[32][33];
  int bid = blockIdx.x;
  int tid = threadIdx.x;
  int kb = (bid & 31) * 32;          // K/32 = 32
  int nb = (bid >> 5) * 32;          // N/32 = 64
  int r  = tid >> 3;                 // 0..31
  int c4 = (tid & 7) * 4;            // 0..28
  float4 v = *(const float4*)&kvk[(size_t)(kb + r) * N_ + nb + c4];
  tile[r][c4+0] = v.x; tile[r][c4+1] = v.y; tile[r][c4+2] = v.z; tile[r][c4+3] = v.w;
  __syncthreads();
  uint2 o;
  o.x = pk_bf16(tile[c4+0][r], tile[c4+1][r]);
  o.y = pk_bf16(tile[c4+2][r], tile[c4+3][r]);
  *(uint2*)&wBt[(size_t)(nb + r) * K_ + kb + c4] = o;
}

// ---------------- GEMM (A from f32, cast in staging) + relu + s-dot + v-store + pass1 ----
// 1D grid 2048, XCD-swizzled: g -> xcd=g&7, slot=g>>3, head=slot&15, mtile=(slot>>4)*8+xcd.
// K-loop: BK=64, single buffer, 2 barriers/iter.
// A: f32 global -> VGPR (coalesced 256B runs) -> cvt_pk bf16 -> ds_write_b64, row-XOR swizzle.
//    Loads for iter i+1 issued before barrier 2 -> fly during iter i's MFMA phase.
// B: global_load_lds from pre-transposed bf16 wBt, same swizzle.
__global__ __launch_bounds__(256)
void gemm_kv(const float* __restrict__ A32, const u16* __restrict__ Bt,
             const float* __restrict__ q,
             float* __restrict__ sbuf, u16* __restrict__ vbuf,
             float* __restrict__ aggM, float* __restrict__ aggU,
             float* __restrict__ aggW) {
  __shared__ __align__(16) char smem[33536];
  // K-loop: lA [128][64] u16 @0 (16 KB), lB [128][64] u16 @16384 (16 KB)
  // epilogue overlay: vtile u16[128][72] @0 (18432 B), sred float[128][17] @18432 (8704 B)
  u16*   lA    = (u16*)smem;
  u16*   lB    = (u16*)(smem + 16384);
  u16*   vtile = (u16*)smem;
  float* sred  = (float*)(smem + 18432);
  float* qs    = (float*)(smem + 32768);   // [64]
  float* sS    = (float*)(smem + 33024);   // [128]

  const int tid  = threadIdx.x;
  const int wave = tid >> 6;
  const int lane = tid & 63;
  const int quad = lane >> 4;
  const int l16  = lane & 15;

  const int g    = blockIdx.x;
  const int xcd  = g & 7;
  const int slot = g >> 3;
  const int h    = slot & 15;
  const int mt   = (slot >> 4) * 8 + xcd;   // 0..127
  const int bm = mt * 128;
  const int bn = h * 128;
  const int wm = (wave >> 1) * 64;
  const int wn = (wave & 1) * 64;

  if (tid < D_) qs[tid] = q[h * D_ + tid];

  // ---- A staging geometry: 8 sweeps of 16 rows; thread -> (row=ar, 16B granule akp)
  const int ar   = tid >> 4;            // 0..15 row within sweep
  const int akp  = tid & 15;
  const int ach  = akp >> 1;            // global k-chunk (8 elems)
  const int asub = akp & 1;             // which half of the chunk (4 elems)
  const float* aGp = A32 + (size_t)(bm + ar) * K_ + ach*8 + asub*4;
  const int aLp = ar*64 + ((ach ^ (ar & 7)) * 8) + asub*4;   // u16 elem offset, sweep-invariant

  // ---- B staging: wave w rows [w*32,w*32+32), 4 calls x 8 rows, row-XOR swizzle
  const int r8 = lane >> 3;
  const int k8 = lane & 7;
  const int gk = (k8 ^ r8) * 8;
  const u16* gbBase = Bt + (size_t)(bn + wave*32 + r8) * K_ + gk;

  // fragment read LDS chunk slots (conflict-free per 8-lane phase):
  const int fs0 = ((quad    ) ^ (l16 & 7)) * 8;   // k half 0
  const int fs1 = ((quad + 4) ^ (l16 & 7)) * 8;   // k half 1

  float4_t acc[4][4] = {};

  float4 aReg[8];
#pragma unroll
  for (int s = 0; s < 8; ++s)
    aReg[s] = *(const float4*)(aGp + (size_t)s * 16 * K_);

  for (int it = 0; it < 16; ++it) {
    const int k0 = it * 64;
    __syncthreads();                 // prior iter's LDS reads done
    // A: cvt + LDS write (aReg loaded last iter, latency covered by MFMA phase)
#pragma unroll
    for (int s = 0; s < 8; ++s) {
      float4 av = aReg[s];
      uint2 o;
      o.x = pk_bf16(av.x, av.y);
      o.y = pk_bf16(av.z, av.w);
      *(uint2*)&lA[s*1024 + aLp] = o;
    }
    // B: async DMA
#pragma unroll
    for (int call = 0; call < 4; ++call)
      g2l16(gbBase + k0 + (size_t)(call*8) * K_, lB + (wave*32 + call*8) * 64);
    // A loads for next iter — in flight across barrier + MFMA phase
    if (it < 15) {
#pragma unroll
      for (int s = 0; s < 8; ++s)
        aReg[s] = *(const float4*)(aGp + (size_t)s * 16 * K_ + k0 + 64);
    }
    __syncthreads();                 // drain -> LDS visible

    short8_t af[4][2], bfr[4][2];
#pragma unroll
    for (int i = 0; i < 4; ++i) {
      int row = (wm + i*16 + l16) * 64;
      af[i][0] = *(const short8_t*)&lA[row + fs0];
      af[i][1] = *(const short8_t*)&lA[row + fs1];
    }
#pragma unroll
    for (int j = 0; j < 4; ++j) {
      int row = (wn + j*16 + l16) * 64;
      bfr[j][0] = *(const short8_t*)&lB[row + fs0];
      bfr[j][1] = *(const short8_t*)&lB[row + fs1];
    }
#pragma unroll
    for (int t = 0; t < 2; ++t)
#pragma unroll
      for (int i = 0; i < 4; ++i)
#pragma unroll
        for (int j = 0; j < 4; ++j)
          acc[i][j] = __builtin_amdgcn_mfma_f32_16x16x32_bf16(af[i][t], bfr[j][t], acc[i][j], 0, 0, 0);
  }

  __syncthreads();   // K-loop done; smem reused as vtile/sred

  // C/D layout: col(n)=l16, row(m)=quad*4+reg. n parity = l16 parity:
  // odd l16 -> v columns (stage bf16 to vtile), even l16 -> k columns (dot with q).
  if (l16 & 1) {
#pragma unroll
    for (int j = 0; j < 4; ++j) {
      int d = ((wn + j*16 + l16) & 127) >> 1;
#pragma unroll
      for (int i = 0; i < 4; ++i)
#pragma unroll
        for (int r = 0; r < 4; ++r) {
          int t = wm + i*16 + quad*4 + r;
          vtile[t*72 + d] = f2bf(fmaxf(acc[i][j][r], 0.f));
        }
    }
  } else {
    int slot2 = (wn >> 3) + (l16 >> 1);   // 0..15
#pragma unroll
    for (int i = 0; i < 4; ++i)
#pragma unroll
      for (int r = 0; r < 4; ++r) {
        int t = wm + i*16 + quad*4 + r;
        float p = 0.f;
#pragma unroll
        for (int j = 0; j < 4; ++j) {
          int d = ((wn + j*16 + l16) & 127) >> 1;
          p += qs[d] * fmaxf(acc[i][j][r], 0.f);
        }
        sred[t*17 + slot2] = p;
      }
  }
  __syncthreads();

  const int b   = mt >> 5;            // 32 m-tiles per batch
  const int tt0 = (mt & 31) * 128;    // t offset within batch
  const int bh  = b * H_ + h;

  // s reduction -> sS + sbuf
  if (tid < 128) {
    float ssum = 0.f;
#pragma unroll
    for (int k = 0; k < 16; ++k) ssum += sred[tid*17 + k];
    sS[tid] = ssum;
    sbuf[(size_t)bh * T_ + tt0 + tid] = ssum;
  }
  __syncthreads();

  if (wave < 2) {
    // fused pass1: scan chunk `wave` (local t = wave*64 .. +63)
    int d = lane;
    float m = -INFINITY, u = 0.f, w = 0.f;
#pragma unroll 4
    for (int i = 0; i < CL_; ++i) {
      int t = wave * CL_ + i;
      float si = sS[t];
      float v  = bf2f(vtile[t*72 + d]);
      float mn    = fmaxf(m, si);
      float alpha = __expf(m - mn);
      float p     = __expf(si - mn);
      u = u * alpha + p;
      w = w * alpha + p * v;
      m = mn;
    }
    int blk = bh * C_ + (mt & 31) * 2 + wave;
    aggW[(size_t)blk * D_ + d] = w;
    if (d == 0) { aggM[blk] = m; aggU[blk] = u; }
  } else {
    // coalesced v store: v[b][h][tt0:tt0+128][:] (contiguous 16 KB)
    int idx = tid - 128;               // 0..127
    int d0  = (idx & 7) * 8;
    int tr  = idx >> 3;                // 0..15
    u16* vg = vbuf + ((size_t)bh * T_ + tt0) * D_;
#pragma unroll
    for (int itv = 0; itv < 8; ++itv) {
      int t = tr + 16*itv;
      uint4 val = *(const uint4*)&vtile[t*72 + d0];
      *(uint4*)&vg[(size_t)t * D_ + d0] = val;
    }
  }
}

// ---------------- pass 3: prefix + seeded scan + h-reduction ----------------
__global__ __launch_bounds__(1024)
void scan_pass3(const u16* __restrict__ vbuf, const float* __restrict__ sbuf,
                const float* __restrict__ aggM, const float* __restrict__ aggU,
                const float* __restrict__ aggW, float* __restrict__ out) {
  __shared__ float sS[H_][CL_];         // 4 KB
  __shared__ float wbuf[H_][8][D_ + 1]; // 33.3 KB
  int bc = blockIdx.x;
  int b  = bc >> 6;
  int c  = bc & (C_ - 1);
  int tid  = threadIdx.x;
  int h    = tid >> 6;
  int lane = tid & 63;
  int bh   = b * H_ + h;
  int t0   = c * CL_;

  sS[h][lane] = sbuf[(size_t)bh * T_ + t0 + lane];

  // exclusive prefix over chunks [0,c) of this chain
  float m = -INFINITY, u = 0.f, w = 0.f;
  for (int j = 0; j < c; ++j) {
    int idx = bh * C_ + j;
    float Mc = aggM[idx];
    float Uc = aggU[idx];
    float Wc = aggW[(size_t)idx * D_ + lane];
    float mn = fmaxf(m, Mc);
    float ea = __expf(m - mn);
    float eb = __expf(Mc - mn);
    u = u * ea + Uc * eb;
    w = w * ea + Wc * eb;
    m = mn;
  }
  __syncthreads();

  const u16* vp = vbuf + ((size_t)bh * T_ + t0) * D_ + lane;
  for (int gg = 0; gg < 8; ++gg) {
#pragma unroll
    for (int ii = 0; ii < 8; ++ii) {
      int i = gg * 8 + ii;
      float si = sS[h][i];
      float v  = bf2f(vp[i * D_]);
      float mn    = fmaxf(m, si);
      float alpha = __expf(m - mn);
      float p     = __expf(si - mn);
      u = u * alpha + p;
      w = w * alpha + p * v;
      m = mn;
      wbuf[h][ii][lane] = __fdividef(w, u);
    }
    __syncthreads();
    if (tid < 512) {
      int ii = tid >> 6, dd = tid & 63;
      float acc = 0.f;
#pragma unroll
      for (int hh = 0; hh < H_; ++hh) acc += wbuf[hh][ii][dd];
      out[((size_t)b * T_ + t0 + gg*8 + ii) * D_ + dd] = acc;
    }
    __syncthreads();
  }
}

extern "C" void kernel_launch(void* const* d_in, const int* in_sizes, int n_in,
                              void* d_out, int out_size, void* d_ws, size_t ws_size,
                              hipStream_t stream) {
  const float* inputs = (const float*)d_in[0];   // (B,T,DIN)
  const float* kvk    = (const float*)d_in[1];   // (DIN,H,D,2)
  const float* qk     = (const float*)d_in[2];   // (H,D)
  float* out = (float*)d_out;
  char* ws = (char*)d_ws;

  u16*   wBt  = (u16*)ws;                       //  4,194,304 B  weights bf16 [N][K]
  u16*   vb   = (u16*)(ws + 4194304);           // 33,554,432 B  v bf16 [b,h,t,d]
  float* sb   = (float*)(ws + 37748736);        //  1,048,576 B  s [b,h,t]
  float* aggM = (float*)(ws + 38797312);        //     16,384 B
  float* aggU = (float*)(ws + 38813696);        //     16,384 B
  float* aggW = (float*)(ws + 38830080);        //  1,048,576 B  (ends ~39.9 MB)

  prep<<<2048, 256, 0, stream>>>(kvk, wBt);
  gemm_kv<<<2048, 256, 0, stream>>>(inputs, wBt, qk, sb, vb, aggM, aggU, aggW);
  scan_pass3<<<B_*C_, 1024, 0, stream>>>(vb, sb, aggM, aggU, aggW, out);
}

// Round 10
// 241.872 us; speedup vs baseline: 1.5462x; 1.0468x over previous
//
#include <hip/hip_runtime.h>
#include <hip/hip_bf16.h>
#include <math.h>

#define B_   4
#define T_   4096
#define DIN_ 1024
#define H_   16
#define D_   64
#define M_   (B_*T_)      // 16384
#define N_   (H_*D_*2)    // 2048
#define K_   DIN_         // 1024
#define C_   64           // scan chunks per (b,h) chain
#define CL_  (T_/C_)      // 64 steps per chunk

typedef unsigned short u16;
typedef __attribute__((ext_vector_type(8))) short short8_t;
typedef __attribute__((ext_vector_type(4))) float float4_t;
typedef union { unsigned u[4]; short8_t s; } s8cast;

__device__ __forceinline__ u16 f2bf(float f) {
  unsigned int x = __float_as_uint(f);
  x += 0x7fffu + ((x >> 16) & 1u);   // round-to-nearest-even (finite inputs)
  return (u16)(x >> 16);
}
__device__ __forceinline__ float bf2f(unsigned int u) {
  return __uint_as_float((u & 0xffffu) << 16);
}
// pack two f32 -> bf16x2 (RNE)
__device__ __forceinline__ unsigned pk_bf16(float x, float y) {
  float2 f; f.x = x; f.y = y;
  union { __hip_bfloat162 h2; unsigned u; } c;
  c.h2 = __float22bfloat162_rn(f);
  return c.u;
}

// async global->LDS, 16 B per lane. LDS dest = wave-uniform base + lane*16.
__device__ __forceinline__ void g2l16(const void* g, void* l) {
  __builtin_amdgcn_global_load_lds(
      (const __attribute__((address_space(1))) void*)g,
      (__attribute__((address_space(3))) void*)l, 16, 0, 0);
}

// ---------------- prep: cast-transpose weights only ----------------
// weights [K][N] f32 -> [N][K] bf16 via 32x32 LDS tile; 2048 blocks
__global__ __launch_bounds__(256)
void prep(const float* __restrict__ kvk, u16* __restrict__ wBt) {
  __shared__ float tile[32][33];
  int bid = blockIdx.x;
  int tid = threadIdx.x;
  int kb = (bid & 31) * 32;          // K/32 = 32
  int nb = (bid >> 5) * 32;          // N/32 = 64
  int r  = tid >> 3;                 // 0..31
  int c4 = (tid & 7) * 4;            // 0..28
  float4 v = *(const float4*)&kvk[(size_t)(kb + r) * N_ + nb + c4];
  tile[r][c4+0] = v.x; tile[r][c4+1] = v.y; tile[r][c4+2] = v.z; tile[r][c4+3] = v.w;
  __syncthreads();
  uint2 o;
  o.x = pk_bf16(tile[c4+0][r], tile[c4+1][r]);
  o.y = pk_bf16(tile[c4+2][r], tile[c4+3][r]);
  *(uint2*)&wBt[(size_t)(nb + r) * K_ + kb + c4] = o;
}

// ---------------- GEMM (A f32 DMA-staged, cvt at fragment read) + fused epilogue ----
// 1D grid 2048, XCD-swizzled: g -> xcd=g&7, slot=g>>3, head=slot&15, mtile=(slot>>4)*8+xcd.
// K-loop: BK=64, single buffer, 2 barriers/iter (R7 structure — proven best).
// A: raw f32 -> LDS via global_load_lds (async DMA, drains at the barrier we already pay);
//    16B-granule XOR swizzle (slot = g ^ (R&15)); cvt_pk->bf16 at fragment read.
// B: global_load_lds from pre-transposed bf16 wBt, row-XOR swizzle (R7).
__global__ __launch_bounds__(256)
void gemm_kv(const float* __restrict__ A32, const u16* __restrict__ Bt,
             const float* __restrict__ q,
             float* __restrict__ sbuf, u16* __restrict__ vbuf,
             float* __restrict__ aggM, float* __restrict__ aggU,
             float* __restrict__ aggW) {
  __shared__ __align__(16) char smem[49920];
  // K-loop: lAf f32[128][64] @0 (32 KB), lB u16[128][64] @32768 (16 KB)
  // epilogue overlay: vtile u16[128][72] @0 (18432 B), sred float[128][17] @18432 (8704 B)
  float* lAf   = (float*)smem;
  u16*   lB    = (u16*)(smem + 32768);
  u16*   vtile = (u16*)smem;
  float* sred  = (float*)(smem + 18432);
  float* qs    = (float*)(smem + 49152);   // [64]
  float* sS    = (float*)(smem + 49408);   // [128]

  const int tid  = threadIdx.x;
  const int wave = tid >> 6;
  const int lane = tid & 63;
  const int quad = lane >> 4;
  const int l16  = lane & 15;

  const int g    = blockIdx.x;
  const int xcd  = g & 7;
  const int slot = g >> 3;
  const int h    = slot & 15;
  const int mt   = (slot >> 4) * 8 + xcd;   // 0..127
  const int bm = mt * 128;
  const int bn = h * 128;
  const int wm = (wave >> 1) * 64;
  const int wn = (wave & 1) * 64;

  if (tid < D_) qs[tid] = q[h * D_ + tid];

  // ---- A staging: wave w rows [w*32, w*32+32), 8 calls x 4 rows.
  // lane -> r4 = lane>>4 (row within call), gsl = lane&15 (LDS 16B-granule slot).
  // Global granule fetched for slot gsl of row R: gsl ^ (R & 15), R&15 = (call*4 + r4)&15.
  const int r4a = lane >> 4;
  const int gsl = lane & 15;
  const float* aRowBase = A32 + (size_t)(bm + wave*32 + r4a) * K_;

  // ---- B staging: wave w rows [w*32,w*32+32), 4 calls x 8 rows, row-XOR swizzle (R7)
  const int r8 = lane >> 3;
  const int k8 = lane & 7;
  const int gkb = (k8 ^ r8) * 8;
  const u16* gbBase = Bt + (size_t)(bn + wave*32 + r8) * K_ + gkb;

  float4_t acc[4][4] = {};

  for (int it = 0; it < 16; ++it) {
    const int k0 = it * 64;          // k elems this iter (also f32 offset within A row)
    __syncthreads();                 // prior iter's LDS reads done
    // A: f32 DMA, swizzled granules
#pragma unroll
    for (int call = 0; call < 8; ++call) {
      int gf = (gsl ^ ((call*4 + r4a) & 15)) * 4;   // f32 offset within row segment
      g2l16(aRowBase + (size_t)(call*4) * K_ + k0 + gf,
            lAf + (wave*32 + call*4) * 64);
    }
    // B: bf16 DMA (R7)
#pragma unroll
    for (int call = 0; call < 4; ++call)
      g2l16(gbBase + k0 + (size_t)(call*8) * K_, lB + (wave*32 + call*8) * 64);
    __syncthreads();                 // drain -> LDS visible

    // fragments: A from f32 LDS + cvt; B from bf16 LDS (R7 swizzle)
    short8_t af[4][2], bfr[4][2];
#pragma unroll
    for (int i = 0; i < 4; ++i) {
      int R = wm + i*16 + l16;
#pragma unroll
      for (int t2 = 0; t2 < 2; ++t2) {
        int g0 = 2*quad + 8*t2;      // first 16B granule of this 8-f32 fragment half
        float4 fa = *(const float4*)&lAf[R*64 + ((g0       ^ l16) * 4)];
        float4 fb = *(const float4*)&lAf[R*64 + (((g0 + 1) ^ l16) * 4)];
        s8cast c;
        c.u[0] = pk_bf16(fa.x, fa.y);
        c.u[1] = pk_bf16(fa.z, fa.w);
        c.u[2] = pk_bf16(fb.x, fb.y);
        c.u[3] = pk_bf16(fb.z, fb.w);
        af[i][t2] = c.s;
      }
    }
    const int fs0 = ((quad    ) ^ (l16 & 7)) * 8;
    const int fs1 = ((quad + 4) ^ (l16 & 7)) * 8;
#pragma unroll
    for (int j = 0; j < 4; ++j) {
      int row = (wn + j*16 + l16) * 64;
      bfr[j][0] = *(const short8_t*)&lB[row + fs0];
      bfr[j][1] = *(const short8_t*)&lB[row + fs1];
    }
#pragma unroll
    for (int t2 = 0; t2 < 2; ++t2)
#pragma unroll
      for (int i = 0; i < 4; ++i)
#pragma unroll
        for (int j = 0; j < 4; ++j)
          acc[i][j] = __builtin_amdgcn_mfma_f32_16x16x32_bf16(af[i][t2], bfr[j][t2], acc[i][j], 0, 0, 0);
  }

  __syncthreads();   // K-loop done; smem reused as vtile/sred

  // C/D layout: col(n)=l16, row(m)=quad*4+reg. n parity = l16 parity:
  // odd l16 -> v columns (stage bf16 to vtile), even l16 -> k columns (dot with q).
  if (l16 & 1) {
#pragma unroll
    for (int j = 0; j < 4; ++j) {
      int d = ((wn + j*16 + l16) & 127) >> 1;
#pragma unroll
      for (int i = 0; i < 4; ++i)
#pragma unroll
        for (int r = 0; r < 4; ++r) {
          int t = wm + i*16 + quad*4 + r;
          vtile[t*72 + d] = f2bf(fmaxf(acc[i][j][r], 0.f));
        }
    }
  } else {
    int slot2 = (wn >> 3) + (l16 >> 1);   // 0..15
#pragma unroll
    for (int i = 0; i < 4; ++i)
#pragma unroll
      for (int r = 0; r < 4; ++r) {
        int t = wm + i*16 + quad*4 + r;
        float p = 0.f;
#pragma unroll
        for (int j = 0; j < 4; ++j) {
          int d = ((wn + j*16 + l16) & 127) >> 1;
          p += qs[d] * fmaxf(acc[i][j][r], 0.f);
        }
        sred[t*17 + slot2] = p;
      }
  }
  __syncthreads();

  const int b   = mt >> 5;            // 32 m-tiles per batch
  const int tt0 = (mt & 31) * 128;    // t offset within batch
  const int bh  = b * H_ + h;

  // s reduction -> sS + sbuf
  if (tid < 128) {
    float ssum = 0.f;
#pragma unroll
    for (int k = 0; k < 16; ++k) ssum += sred[tid*17 + k];
    sS[tid] = ssum;
    sbuf[(size_t)bh * T_ + tt0 + tid] = ssum;
  }
  __syncthreads();

  if (wave < 2) {
    // fused pass1: scan chunk `wave` (local t = wave*64 .. +63)
    int d = lane;
    float m = -INFINITY, u = 0.f, w = 0.f;
#pragma unroll 4
    for (int i = 0; i < CL_; ++i) {
      int t = wave * CL_ + i;
      float si = sS[t];
      float v  = bf2f(vtile[t*72 + d]);
      float mn    = fmaxf(m, si);
      float alpha = __expf(m - mn);
      float p     = __expf(si - mn);
      u = u * alpha + p;
      w = w * alpha + p * v;
      m = mn;
    }
    int blk = bh * C_ + (mt & 31) * 2 + wave;
    aggW[(size_t)blk * D_ + d] = w;
    if (d == 0) { aggM[blk] = m; aggU[blk] = u; }
  } else {
    // coalesced v store: v[b][h][tt0:tt0+128][:] (contiguous 16 KB)
    int idx = tid - 128;               // 0..127
    int d0  = (idx & 7) * 8;
    int tr  = idx >> 3;                // 0..15
    u16* vg = vbuf + ((size_t)bh * T_ + tt0) * D_;
#pragma unroll
    for (int itv = 0; itv < 8; ++itv) {
      int t = tr + 16*itv;
      uint4 val = *(const uint4*)&vtile[t*72 + d0];
      *(uint4*)&vg[(size_t)t * D_ + d0] = val;
    }
  }
}

// ---------------- pass 3: prefix + seeded scan + h-reduction ----------------
__global__ __launch_bounds__(1024)
void scan_pass3(const u16* __restrict__ vbuf, const float* __restrict__ sbuf,
                const float* __restrict__ aggM, const float* __restrict__ aggU,
                const float* __restrict__ aggW, float* __restrict__ out) {
  __shared__ float sS[H_][CL_];         // 4 KB
  __shared__ float wbuf[H_][8][D_ + 1]; // 33.3 KB
  int bc = blockIdx.x;
  int b  = bc >> 6;
  int c  = bc & (C_ - 1);
  int tid  = threadIdx.x;
  int h    = tid >> 6;
  int lane = tid & 63;
  int bh   = b * H_ + h;
  int t0   = c * CL_;

  sS[h][lane] = sbuf[(size_t)bh * T_ + t0 + lane];

  // exclusive prefix over chunks [0,c) of this chain
  float m = -INFINITY, u = 0.f, w = 0.f;
  for (int j = 0; j < c; ++j) {
    int idx = bh * C_ + j;
    float Mc = aggM[idx];
    float Uc = aggU[idx];
    float Wc = aggW[(size_t)idx * D_ + lane];
    float mn = fmaxf(m, Mc);
    float ea = __expf(m - mn);
    float eb = __expf(Mc - mn);
    u = u * ea + Uc * eb;
    w = w * ea + Wc * eb;
    m = mn;
  }
  __syncthreads();

  const u16* vp = vbuf + ((size_t)bh * T_ + t0) * D_ + lane;
  for (int gg = 0; gg < 8; ++gg) {
#pragma unroll
    for (int ii = 0; ii < 8; ++ii) {
      int i = gg * 8 + ii;
      float si = sS[h][i];
      float v  = bf2f(vp[i * D_]);
      float mn    = fmaxf(m, si);
      float alpha = __expf(m - mn);
      float p     = __expf(si - mn);
      u = u * alpha + p;
      w = w * alpha + p * v;
      m = mn;
      wbuf[h][ii][lane] = __fdividef(w, u);
    }
    __syncthreads();
    if (tid < 512) {
      int ii = tid >> 6, dd = tid & 63;
      float acc = 0.f;
#pragma unroll
      for (int hh = 0; hh < H_; ++hh) acc += wbuf[hh][ii][dd];
      out[((size_t)b * T_ + t0 + gg*8 + ii) * D_ + dd] = acc;
    }
    __syncthreads();
  }
}

extern "C" void kernel_launch(void* const* d_in, const int* in_sizes, int n_in,
                              void* d_out, int out_size, void* d_ws, size_t ws_size,
                              hipStream_t stream) {
  const float* inputs = (const float*)d_in[0];   // (B,T,DIN)
  const float* kvk    = (const float*)d_in[1];   // (DIN,H,D,2)
  const float* qk     = (const float*)d_in[2];   // (H,D)
  float* out = (float*)d_out;
  char* ws = (char*)d_ws;

  u16*   wBt  = (u16*)ws;                       //  4,194,304 B  weights bf16 [N][K]
  u16*   vb   = (u16*)(ws + 4194304);           // 33,554,432 B  v bf16 [b,h,t,d]
  float* sb   = (float*)(ws + 37748736);        //  1,048,576 B  s [b,h,t]
  float* aggM = (float*)(ws + 38797312);        //     16,384 B
  float* aggU = (float*)(ws + 38813696);        //     16,384 B
  float* aggW = (float*)(ws + 38830080);        //  1,048,576 B  (ends ~39.9 MB)

  prep<<<2048, 256, 0, stream>>>(kvk, wBt);
  gemm_kv<<<2048, 256, 0, stream>>>(inputs, wBt, qk, sb, vb, aggM, aggU, aggW);
  scan_pass3<<<B_*C_, 1024, 0, stream>>>(vb, sb, aggM, aggU, aggW, out);
}

// Round 11
// 217.480 us; speedup vs baseline: 1.7196x; 1.1122x over previous
//
#include <hip/hip_runtime.h>
#include <hip/hip_bf16.h>
#include <math.h>

#define B_   4
#define T_   4096
#define DIN_ 1024
#define H_   16
#define D_   64
#define M_   (B_*T_)      // 16384
#define N_   (H_*D_*2)    // 2048
#define K_   DIN_         // 1024
#define C_   64           // scan chunks per (b,h) chain
#define CL_  (T_/C_)      // 64 steps per chunk

typedef unsigned short u16;
typedef __attribute__((ext_vector_type(8))) short short8_t;
typedef __attribute__((ext_vector_type(4))) float float4_t;

__device__ __forceinline__ u16 f2bf(float f) {
  unsigned int x = __float_as_uint(f);
  x += 0x7fffu + ((x >> 16) & 1u);   // round-to-nearest-even (finite inputs)
  return (u16)(x >> 16);
}
__device__ __forceinline__ float bf2f(unsigned int u) {
  return __uint_as_float((u & 0xffffu) << 16);
}
__device__ __forceinline__ unsigned pk_bf16(float x, float y) {
  float2 f; f.x = x; f.y = y;
  union { __hip_bfloat162 h2; unsigned u; } c;
  c.h2 = __float22bfloat162_rn(f);
  return c.u;
}

// async global->LDS, 16 B per lane. LDS dest = wave-uniform base + lane*16.
__device__ __forceinline__ void g2l16(const u16* g, u16* l) {
  __builtin_amdgcn_global_load_lds(
      (const __attribute__((address_space(1))) void*)g,
      (__attribute__((address_space(3))) void*)l, 16, 0, 0);
}

// ---------------- prep: cast inputs + cast-transpose weights (R7) ----------------
__global__ __launch_bounds__(256)
void prep(const float* __restrict__ inputs, const float* __restrict__ kvk,
          u16* __restrict__ aB, u16* __restrict__ wBt) {
  __shared__ float tile[32][33];
  int bid = blockIdx.x;
  int tid = threadIdx.x;
  if (bid < 8192) {
    int i = bid * 256 + tid;          // over M*K/8
    const float4* src = (const float4*)inputs;
    float4 a = src[2*i], b = src[2*i+1];
    uint4 o;
    o.x = pk_bf16(a.x, a.y);
    o.y = pk_bf16(a.z, a.w);
    o.z = pk_bf16(b.x, b.y);
    o.w = pk_bf16(b.z, b.w);
    ((uint4*)aB)[i] = o;
  } else {
    int b2 = bid - 8192;              // 2048 blocks
    int kb = (b2 & 31) * 32;          // K/32 = 32
    int nb = (b2 >> 5) * 32;          // N/32 = 64
    int r  = tid >> 3;                // 0..31
    int c4 = (tid & 7) * 4;           // 0..28
    float4 v = *(const float4*)&kvk[(size_t)(kb + r) * N_ + nb + c4];
    tile[r][c4+0] = v.x; tile[r][c4+1] = v.y; tile[r][c4+2] = v.z; tile[r][c4+3] = v.w;
    __syncthreads();
    uint2 o;
    o.x = pk_bf16(tile[c4+0][r], tile[c4+1][r]);
    o.y = pk_bf16(tile[c4+2][r], tile[c4+3][r]);
    *(uint2*)&wBt[(size_t)(nb + r) * K_ + kb + c4] = o;
  }
}

// ---------------- GEMM (R7 K-loop) + relu + p=exp(s) + v-store + additive pass1 ----
// 1D grid 2048, XCD-swizzled. K-loop: BK=64, single buffer, 2 barriers/iter,
// all-bf16 global_load_lds staging, row-XOR swizzle (proven-best config).
// Epilogue: s-dot -> p=exp(clamp(s)) -> pbuf; v -> vtile -> vbuf;
// per-chunk ADDITIVE aggregates U=sum p, W=sum p*v (no max-trick).
__global__ __launch_bounds__(256)
void gemm_kv(const u16* __restrict__ A, const u16* __restrict__ Bt,
             const float* __restrict__ q,
             float* __restrict__ pbuf, u16* __restrict__ vbuf,
             float* __restrict__ aggU, float* __restrict__ aggW) {
  __shared__ __align__(16) char smem[33536];
  // K-loop: lA [128][64] u16 @0 (16 KB), lB [128][64] u16 @16384 (16 KB)
  // epilogue overlay: vtile u16[128][72] @0 (18432 B), sred float[128][17] @18432 (8704 B)
  u16*   lA    = (u16*)smem;
  u16*   lB    = (u16*)(smem + 16384);
  u16*   vtile = (u16*)smem;
  float* sred  = (float*)(smem + 18432);
  float* qs    = (float*)(smem + 32768);   // [64]
  float* pS    = (float*)(smem + 33024);   // [128]

  const int tid  = threadIdx.x;
  const int wave = tid >> 6;
  const int lane = tid & 63;
  const int quad = lane >> 4;
  const int l16  = lane & 15;

  const int g    = blockIdx.x;
  const int xcd  = g & 7;
  const int slot = g >> 3;
  const int h    = slot & 15;
  const int mt   = (slot >> 4) * 8 + xcd;   // 0..127
  const int bm = mt * 128;
  const int bn = h * 128;
  const int wm = (wave >> 1) * 64;
  const int wn = (wave & 1) * 64;

  if (tid < D_) qs[tid] = q[h * D_ + tid];

  // staging: wave w rows [w*32,w*32+32), 4 calls x 8 rows, row-XOR swizzle
  const int r8 = lane >> 3;
  const int k8 = lane & 7;
  const int gk = (k8 ^ r8) * 8;
  const u16* gaBase = A  + (size_t)(bm + wave*32 + r8) * K_ + gk;
  const u16* gbBase = Bt + (size_t)(bn + wave*32 + r8) * K_ + gk;

  // fragment read LDS chunk slots (conflict-free per 8-lane phase):
  const int fs0 = ((quad    ) ^ (l16 & 7)) * 8;   // k half 0
  const int fs1 = ((quad + 4) ^ (l16 & 7)) * 8;   // k half 1

  float4_t acc[4][4] = {};

  for (int k0 = 0; k0 < K_; k0 += 64) {
    __syncthreads();                 // prior iter's LDS reads done
#pragma unroll
    for (int call = 0; call < 4; ++call) {
      g2l16(gaBase + k0 + (size_t)(call*8) * K_, lA + (wave*32 + call*8) * 64);
      g2l16(gbBase + k0 + (size_t)(call*8) * K_, lB + (wave*32 + call*8) * 64);
    }
    __syncthreads();                 // drain -> LDS visible

    short8_t af[4][2], bfr[4][2];
#pragma unroll
    for (int i = 0; i < 4; ++i) {
      int row = (wm + i*16 + l16) * 64;
      af[i][0] = *(const short8_t*)&lA[row + fs0];
      af[i][1] = *(const short8_t*)&lA[row + fs1];
    }
#pragma unroll
    for (int j = 0; j < 4; ++j) {
      int row = (wn + j*16 + l16) * 64;
      bfr[j][0] = *(const short8_t*)&lB[row + fs0];
      bfr[j][1] = *(const short8_t*)&lB[row + fs1];
    }
#pragma unroll
    for (int t = 0; t < 2; ++t)
#pragma unroll
      for (int i = 0; i < 4; ++i)
#pragma unroll
        for (int j = 0; j < 4; ++j)
          acc[i][j] = __builtin_amdgcn_mfma_f32_16x16x32_bf16(af[i][t], bfr[j][t], acc[i][j], 0, 0, 0);
  }

  __syncthreads();   // K-loop done; smem reused as vtile/sred

  // C/D layout: col(n)=l16, row(m)=quad*4+reg. n parity = l16 parity:
  // odd l16 -> v columns (stage bf16 to vtile), even l16 -> k columns (dot with q).
  if (l16 & 1) {
#pragma unroll
    for (int j = 0; j < 4; ++j) {
      int d = ((wn + j*16 + l16) & 127) >> 1;
#pragma unroll
      for (int i = 0; i < 4; ++i)
#pragma unroll
        for (int r = 0; r < 4; ++r) {
          int t = wm + i*16 + quad*4 + r;
          vtile[t*72 + d] = f2bf(fmaxf(acc[i][j][r], 0.f));
        }
    }
  } else {
    int slot2 = (wn >> 3) + (l16 >> 1);   // 0..15
#pragma unroll
    for (int i = 0; i < 4; ++i)
#pragma unroll
      for (int r = 0; r < 4; ++r) {
        int t = wm + i*16 + quad*4 + r;
        float p = 0.f;
#pragma unroll
        for (int j = 0; j < 4; ++j) {
          int d = ((wn + j*16 + l16) & 127) >> 1;
          p += qs[d] * fmaxf(acc[i][j][r], 0.f);
        }
        sred[t*17 + slot2] = p;
      }
  }
  __syncthreads();

  const int b   = mt >> 5;            // 32 m-tiles per batch
  const int tt0 = (mt & 31) * 128;    // t offset within batch
  const int bh  = b * H_ + h;

  // s reduction -> p = exp(clamp(s)) -> pS + pbuf
  if (tid < 128) {
    float ssum = 0.f;
#pragma unroll
    for (int k = 0; k < 16; ++k) ssum += sred[tid*17 + k];
    float p = __expf(fminf(fmaxf(ssum, -60.f), 60.f));
    pS[tid] = p;
    pbuf[(size_t)bh * T_ + tt0 + tid] = p;
  }
  __syncthreads();

  if (wave < 2) {
    // fused pass1 (additive): chunk sums U = sum p, W[d] = sum p*v
    int d = lane;
    float U = 0.f, W = 0.f;
#pragma unroll 4
    for (int i = 0; i < CL_; ++i) {
      int t = wave * CL_ + i;
      float p = pS[t];
      float v = bf2f(vtile[t*72 + d]);
      U += p;
      W += p * v;
    }
    int blk = bh * C_ + (mt & 31) * 2 + wave;
    aggW[(size_t)blk * D_ + d] = W;
    if (d == 0) aggU[blk] = U;
  } else {
    // coalesced v store: v[b][h][tt0:tt0+128][:] (contiguous 16 KB)
    int idx = tid - 128;               // 0..127
    int d0  = (idx & 7) * 8;
    int tr  = idx >> 3;                // 0..15
    u16* vg = vbuf + ((size_t)bh * T_ + tt0) * D_;
#pragma unroll
    for (int itv = 0; itv < 8; ++itv) {
      int t = tr + 16*itv;
      uint4 val = *(const uint4*)&vtile[t*72 + d0];
      *(uint4*)&vg[(size_t)t * D_ + d0] = val;
    }
  }
}

// ---------------- pass 3: additive prefix + seeded scan + h-reduction ----------------
__global__ __launch_bounds__(1024)
void scan_pass3(const u16* __restrict__ vbuf, const float* __restrict__ pbuf,
                const float* __restrict__ aggU, const float* __restrict__ aggW,
                float* __restrict__ out) {
  __shared__ float pS[H_][CL_];         // 4 KB
  __shared__ float wbuf[H_][8][D_ + 1]; // 33.3 KB
  int bc = blockIdx.x;
  int b  = bc >> 6;
  int c  = bc & (C_ - 1);
  int tid  = threadIdx.x;
  int h    = tid >> 6;
  int lane = tid & 63;
  int bh   = b * H_ + h;
  int t0   = c * CL_;

  pS[h][lane] = pbuf[(size_t)bh * T_ + t0 + lane];

  // additive exclusive prefix over chunks [0,c): independent loads, pipelines freely
  float U = 0.f, W = 0.f;
  for (int j = 0; j < c; ++j) {
    int idx = bh * C_ + j;
    U += aggU[idx];
    W += aggW[(size_t)idx * D_ + lane];
  }
  __syncthreads();

  const u16* vp = vbuf + ((size_t)bh * T_ + t0) * D_ + lane;
  for (int gg = 0; gg < 8; ++gg) {
#pragma unroll
    for (int ii = 0; ii < 8; ++ii) {
      int i = gg * 8 + ii;
      float p = pS[h][i];
      float v = bf2f(vp[i * D_]);
      U += p;
      W += p * v;
      wbuf[h][ii][lane] = __fdividef(W, U);
    }
    __syncthreads();
    if (tid < 512) {
      int ii = tid >> 6, dd = tid & 63;
      float acc = 0.f;
#pragma unroll
      for (int hh = 0; hh < H_; ++hh) acc += wbuf[hh][ii][dd];
      out[((size_t)b * T_ + t0 + gg*8 + ii) * D_ + dd] = acc;
    }
    __syncthreads();
  }
}

extern "C" void kernel_launch(void* const* d_in, const int* in_sizes, int n_in,
                              void* d_out, int out_size, void* d_ws, size_t ws_size,
                              hipStream_t stream) {
  const float* inputs = (const float*)d_in[0];   // (B,T,DIN)
  const float* kvk    = (const float*)d_in[1];   // (DIN,H,D,2)
  const float* qk     = (const float*)d_in[2];   // (H,D)
  float* out = (float*)d_out;
  char* ws = (char*)d_ws;

  u16*   aB   = (u16*)ws;                       // 33,554,432 B  inputs bf16 [M][K]
  u16*   wBt  = (u16*)(ws + 33554432);          //  4,194,304 B  weights bf16 [N][K]
  u16*   vb   = (u16*)(ws + 37748736);          // 33,554,432 B  v bf16 [b,h,t,d]
  float* pb   = (float*)(ws + 71303168);        //  1,048,576 B  p=exp(s) [b,h,t]
  float* aggU = (float*)(ws + 72351744);        //     16,384 B
  float* aggW = (float*)(ws + 72368128);        //  1,048,576 B  (ends ~73.4 MB)

  prep<<<10240, 256, 0, stream>>>(inputs, kvk, aB, wBt);
  gemm_kv<<<2048, 256, 0, stream>>>(aB, wBt, qk, pb, vb, aggU, aggW);
  scan_pass3<<<B_*C_, 1024, 0, stream>>>(vb, pb, aggU, aggW, out);
}